// Round 2
// baseline (358.134 us; speedup 1.0000x reference)
//
#include <hip/hip_runtime.h>

// SelfInteraction on MI355X.
// R1: (a) algebraic fold W2[u,v,w] = W_sv[u,v,w] + W_vs[v,u,w]  => 8 -> 5 GEMM channels
//     (1/sqrt3 folded into W_vv stream); (b) K-segmented 8-wave balance over the
//     5x512 t-step job space; (c) 2-deep rotating B prefetch.

#define C 128
#define NBATCH 8192

typedef _Float16 f16;
typedef _Float16 f16x8 __attribute__((ext_vector_type(8)));
typedef float f32x4 __attribute__((ext_vector_type(4)));

// ws layout:
// [0, 12MB)  : 3 f16 weight streams (ss, vv*inv_sqrt3, comb), each 2,097,152 f16
//              idx ((((h*4+vb)*128+u)*4+wt)*64+lane)*8+j
//                <-> W[u][vb*32+(lane>>4)*8+j][h*64+wt*16+(lane&15)]
// [12MB,32MB): raw channel sums f32 [5][8192][128]  (ss, vv_scaled, cb0, cb1, cb2)
#define WSTREAM_F16_PER_C (2*4*128*4*64*8)   // 2,097,152 f16 = 4MB
#define NSTREAM 3
#define RAW_OFF_BYTES ((size_t)NSTREAM*WSTREAM_F16_PER_C*2)  // 12 MB

__device__ __forceinline__ f16x8 splat8(f16 v) { return (f16x8){v, v, v, v, v, v, v, v}; }
union U16x8 { uint4 u; f16x8 h; };
__device__ __forceinline__ f16x8 as_h8(uint4 v) { U16x8 x; x.u = v; return x.h; }
__device__ __forceinline__ f32x4 mfma16(f16x8 a, f16x8 b, f32x4 c) {
    return __builtin_amdgcn_mfma_f32_16x16x32_f16(a, b, c, 0, 0, 0);
}

// ---------------- weight prep ----------------
// grid 384: c = blockIdx>>7 (0=ss, 1=vv*inv_sqrt3, 2=Wsv+Wvs^T), u = blockIdx&127
__global__ __launch_bounds__(256) void prep_weights(
        const float* __restrict__ Wss, const float* __restrict__ Wvv,
        const float* __restrict__ Wsv, const float* __restrict__ Wvs,
        f16* __restrict__ out) {
    __shared__ float lds[128 * 130];
    int c = blockIdx.x >> 7;
    int u = blockIdx.x & 127;
    if (c == 2) {
        for (int i = threadIdx.x; i < 16384; i += 256) {
            int v = i >> 7, w = i & 127;
            lds[v * 130 + w] = Wsv[(size_t)u * 16384 + i] + Wvs[(size_t)v * 16384 + u * 128 + w];
        }
    } else {
        const float* src = (c == 0 ? Wss : Wvv) + (size_t)u * 16384;
        float sc = (c == 0) ? 1.0f : 0.57735026918962576f;
        for (int i = threadIdx.x; i < 16384; i += 256) {
            int v = i >> 7, w = i & 127;
            lds[v * 130 + w] = sc * src[i];
        }
    }
    __syncthreads();
    f16* dst = out + (size_t)c * WSTREAM_F16_PER_C;
    for (int pos = threadIdx.x; pos < 2048; pos += 256) {
        int h = pos >> 10, vb = (pos >> 8) & 3, wt = (pos >> 6) & 3, l = pos & 63;
        int v0 = vb * 32 + (l >> 4) * 8;
        int w = h * 64 + wt * 16 + (l & 15);
        f16x8 vals;
#pragma unroll
        for (int j = 0; j < 8; ++j) vals[j] = (f16)lds[(v0 + j) * 130 + w];
        size_t off = ((size_t)(((h * 4 + vb) * 128 + u) * 4 + wt) * 64 + l) * 8;
        *(f16x8*)(dst + off) = vals;
    }
}

// ---------------- GEMM segment bodies ----------------
// rank-1 coefficients: coeff[z,(u,v)] = ps[z,u] * pv[z,v]
__device__ __forceinline__ void run_rank1(const f16* __restrict__ ps, const f16* __restrict__ pv,
        const uint4* __restrict__ bs, int t0, int t1, int l15, int lhi,
        f32x4 (&acc)[4][4]) {
    const uint4* blane = bs + lhi * 16 + l15;
    uint4 b0[4], b1[4];
#pragma unroll
    for (int wt = 0; wt < 4; ++wt) b0[wt] = blane[(size_t)t0 * 256 + wt * 64];
#pragma unroll
    for (int wt = 0; wt < 4; ++wt) b1[wt] = blane[(size_t)(t0 + 1) * 256 + wt * 64];

    f16x8 vva[4];
    int vbc = -1;
#pragma unroll 2
    for (int t = t0; t < t1; ++t) {
        int vb = t >> 7;
        if (vb != vbc) {
            vbc = vb;
#pragma unroll
            for (int s = 0; s < 4; ++s) {
                f16x8 tv;
#pragma unroll
                for (int j = 0; j < 8; ++j) tv[j] = pv[(vb * 32 + lhi * 8 + j) * 64 + s * 16 + l15];
                vva[s] = tv;
            }
        }
        int tp = (t + 2 < t1) ? t + 2 : t;   // clamped prefetch
        uint4 bf[4];
#pragma unroll
        for (int wt = 0; wt < 4; ++wt) bf[wt] = blane[(size_t)tp * 256 + wt * 64];

        int uu = t & 127;
        f16x8 A[4];
#pragma unroll
        for (int s = 0; s < 4; ++s) {
            f16 sc = ps[uu * 64 + s * 16 + l15];
            A[s] = splat8(sc) * vva[s];
        }
#pragma unroll
        for (int wt = 0; wt < 4; ++wt) {
            f16x8 B = as_h8(b0[wt]);
#pragma unroll
            for (int s = 0; s < 4; ++s) acc[s][wt] = mfma16(A[s], B, acc[s][wt]);
        }
#pragma unroll
        for (int wt = 0; wt < 4; ++wt) { b0[wt] = b1[wt]; b1[wt] = bf[wt]; }
    }
}

// vv coefficients: coeff[z,(u,v)] = sum_k x1k[z,u]*x1k[z,v]
__device__ __forceinline__ void run_vv(const f16* __restrict__ x1T,
        const uint4* __restrict__ bs, int t0, int t1, int l15, int lhi,
        f32x4 (&acc)[4][4]) {
    const f16* p0 = x1T;
    const f16* p1 = x1T + 128 * 64;
    const f16* p2 = x1T + 2 * 128 * 64;
    const uint4* blane = bs + lhi * 16 + l15;
    uint4 b0[4], b1[4];
#pragma unroll
    for (int wt = 0; wt < 4; ++wt) b0[wt] = blane[(size_t)t0 * 256 + wt * 64];
#pragma unroll
    for (int wt = 0; wt < 4; ++wt) b1[wt] = blane[(size_t)(t0 + 1) * 256 + wt * 64];

    f16x8 vv0[4], vv1[4], vv2[4];
    int vbc = -1;
#pragma unroll 2
    for (int t = t0; t < t1; ++t) {
        int vb = t >> 7;
        if (vb != vbc) {
            vbc = vb;
#pragma unroll
            for (int s = 0; s < 4; ++s) {
                f16x8 t0v, t1v, t2v;
#pragma unroll
                for (int j = 0; j < 8; ++j) {
                    int vi = (vb * 32 + lhi * 8 + j) * 64 + s * 16 + l15;
                    t0v[j] = p0[vi]; t1v[j] = p1[vi]; t2v[j] = p2[vi];
                }
                vv0[s] = t0v; vv1[s] = t1v; vv2[s] = t2v;
            }
        }
        int tp = (t + 2 < t1) ? t + 2 : t;
        uint4 bf[4];
#pragma unroll
        for (int wt = 0; wt < 4; ++wt) bf[wt] = blane[(size_t)tp * 256 + wt * 64];

        int uu = t & 127;
        f16x8 A[4];
#pragma unroll
        for (int s = 0; s < 4; ++s) {
            int zr = s * 16 + l15;
            f16 a0 = p0[uu * 64 + zr];
            f16 a1 = p1[uu * 64 + zr];
            f16 a2 = p2[uu * 64 + zr];
            A[s] = splat8(a0) * vv0[s] + splat8(a1) * vv1[s] + splat8(a2) * vv2[s];
        }
#pragma unroll
        for (int wt = 0; wt < 4; ++wt) {
            f16x8 B = as_h8(b0[wt]);
#pragma unroll
            for (int s = 0; s < 4; ++s) acc[s][wt] = mfma16(A[s], B, acc[s][wt]);
        }
#pragma unroll
        for (int wt = 0; wt < 4; ++wt) { b0[wt] = b1[wt]; b1[wt] = bf[wt]; }
    }
}

__device__ __forceinline__ void storeTile(float* __restrict__ raw, int c, int zb, int h,
        int l15, int lhi, const f32x4 (&acc)[4][4]) {
#pragma unroll
    for (int s = 0; s < 4; ++s)
#pragma unroll
        for (int wt = 0; wt < 4; ++wt)
#pragma unroll
            for (int i = 0; i < 4; ++i) {
                int z = zb * 64 + s * 16 + lhi * 4 + i;
                int ww = h * 64 + wt * 16 + l15;
                raw[((size_t)c * NBATCH + z) * 128 + ww] = acc[s][wt][i];
            }
}

__device__ __forceinline__ void addTile(float* __restrict__ raw, int c, int zb, int h,
        int l15, int lhi, const f32x4 (&acc)[4][4]) {
#pragma unroll
    for (int s = 0; s < 4; ++s)
#pragma unroll
        for (int wt = 0; wt < 4; ++wt)
#pragma unroll
            for (int i = 0; i < 4; ++i) {
                int z = zb * 64 + s * 16 + lhi * 4 + i;
                int ww = h * 64 + wt * 16 + l15;
                raw[((size_t)c * NBATCH + z) * 128 + ww] += acc[s][wt][i];
            }
}

// ---------------- main fused GEMM kernel ----------------
// grid 256: blockIdx = zb*2 + h. 8 waves; wave w covers global t-range [320w, 320w+320)
// of the concatenated 5-channel job space (512 t-steps each: ss, vv, cb0, cb1, cb2).
__global__ __launch_bounds__(512, 2) void si_main(
        const float* __restrict__ x, const f16* __restrict__ wstream,
        float* __restrict__ raw) {
    __shared__ f16 x0T[128 * 64];       // [c][z]
    __shared__ f16 x1T[3 * 128 * 64];   // [k][v][z]

    int zb = blockIdx.x >> 1;
    int h = blockIdx.x & 1;
    int tid = threadIdx.x;

    for (int i = tid; i < 64 * 512; i += 512) {
        int z = i >> 9, col = i & 511;
        f16 fv = (f16)x[(size_t)(zb * 64 + z) * 512 + col];
        if (col < 128) {
            x0T[col * 64 + z] = fv;
        } else {
            int cc = col - 128;
            int vv_ = cc / 3, k = cc - vv_ * 3;
            x1T[(k * 128 + vv_) * 64 + z] = fv;
        }
    }
    __syncthreads();

    int lane = tid & 63, w = tid >> 6;
    int l15 = lane & 15, lhi = lane >> 4;

    int g0 = w * 320, g1 = g0 + 320;
    int ciA = g0 >> 9;
    int endA = ((ciA + 1) * 512 < g1) ? (ciA + 1) * 512 : g1;
    int a0 = g0 - ciA * 512, a1 = endA - ciA * 512;
    bool hasB = endA < g1;
    int ciB = ciA + 1;
    int bN = g1 - endA;

    f32x4 acc[4][4];
#pragma unroll
    for (int s = 0; s < 4; ++s)
#pragma unroll
        for (int wt = 0; wt < 4; ++wt) acc[s][wt] = (f32x4){0.f, 0.f, 0.f, 0.f};

    auto runSeg = [&](int ci, int s0, int s1) {
        int sidx = (ci == 0) ? 0 : (ci == 1) ? 1 : 2;
        const uint4* bs = (const uint4*)(wstream + (size_t)sidx * WSTREAM_F16_PER_C
                                         + (size_t)h * (WSTREAM_F16_PER_C / 2));
        if (ci == 1) {
            run_vv(x1T, bs, s0, s1, l15, lhi, acc);
        } else {
            const f16* pv = (ci == 0) ? x0T : (x1T + (ci - 2) * (128 * 64));
            run_rank1(x0T, pv, bs, s0, s1, l15, lhi, acc);
        }
    };

    runSeg(ciA, a0, a1);
    if (hasB) {
        storeTile(raw, ciA, zb, h, l15, lhi, acc);   // first write of channel ciA's tile
#pragma unroll
        for (int s = 0; s < 4; ++s)
#pragma unroll
            for (int wt = 0; wt < 4; ++wt) acc[s][wt] = (f32x4){0.f, 0.f, 0.f, 0.f};
        runSeg(ciB, 0, bN);
    }
    int cF = hasB ? ciB : ciA;
    if (w == 7) storeTile(raw, cF, zb, h, l15, lhi, acc);  // cb2 first write

    __threadfence_block();
    __syncthreads();
    // round 1 adders (one per channel, distinct tiles)
    if (w == 0 || w == 1 || w == 3 || w == 4 || w == 6)
        addTile(raw, cF, zb, h, l15, lhi, acc);
    __threadfence_block();
    __syncthreads();
    // round 2 adders
    if (w == 2 || w == 5)
        addTile(raw, cF, zb, h, l15, lhi, acc);
}

// ---------------- finalize ----------------
__global__ __launch_bounds__(64) void si_finalize(const float* __restrict__ raw,
                                                  float* __restrict__ out) {
    const float PW0 = 0.0055242717280199f;   // 1/sqrt(2*128*128) == pw1/sqrt(3)
    int z = blockIdx.x;
    int t = threadIdx.x;
    const size_t CS = (size_t)NBATCH * 128;
    const float* r0 = raw + (size_t)z * 128;

    // scalar output (vv stream already scaled by 1/sqrt3)
    float y0A = PW0 * (r0[t] + r0[CS + t]);
    float y0B = PW0 * (r0[t + 64] + r0[CS + t + 64]);
    float s1 = y0A + y0B, s2 = y0A * y0A + y0B * y0B;
    for (int o = 32; o; o >>= 1) {
        s1 += __shfl_xor(s1, o);
        s2 += __shfl_xor(s2, o);
    }
    float mean = s1 * (1.0f / 128.0f);
    float var = (s2 - 128.0f * mean * mean) * (1.0f / 127.0f);
    float sc = 1.0f / (sqrtf(fmaxf(var, 0.0f)) + 1e-9f);
    out[(size_t)z * 512 + t] = y0A * sc;
    out[(size_t)z * 512 + t + 64] = y0B * sc;

    // vector output (comb = sv + vs already)
    float yA[3], yB[3];
    float nA = 1e-9f, nB = 1e-9f;
#pragma unroll
    for (int k = 0; k < 3; ++k) {
        yA[k] = PW0 * r0[CS * (2 + k) + t];
        yB[k] = PW0 * r0[CS * (2 + k) + t + 64];
        nA += yA[k] * yA[k];
        nB += yB[k] * yB[k];
    }
    nA = sqrtf(nA);
    nB = sqrtf(nB);
    float t1 = nA + nB, t2 = nA * nA + nB * nB;
    for (int o = 32; o; o >>= 1) {
        t1 += __shfl_xor(t1, o);
        t2 += __shfl_xor(t2, o);
    }
    float meanv = t1 * (1.0f / 128.0f);
    float varv = (t2 - 128.0f * meanv * meanv) * (1.0f / 127.0f);
    float sv = 1.0f / (sqrtf(fmaxf(varv, 0.0f)) + 1e-9f);
#pragma unroll
    for (int k = 0; k < 3; ++k) {
        out[(size_t)z * 512 + 128 + t * 3 + k] = yA[k] * sv;
        out[(size_t)z * 512 + 128 + (t + 64) * 3 + k] = yB[k] * sv;
    }
}

extern "C" void kernel_launch(void* const* d_in, const int* in_sizes, int n_in,
                              void* d_out, int out_size, void* d_ws, size_t ws_size,
                              hipStream_t stream) {
    const float* x = (const float*)d_in[0];
    const float* Wss = (const float*)d_in[1];
    const float* Wvv = (const float*)d_in[2];
    const float* Wsv = (const float*)d_in[3];
    const float* Wvs = (const float*)d_in[4];
    f16* wstream = (f16*)d_ws;
    float* raw = (float*)((char*)d_ws + RAW_OFF_BYTES);
    float* out = (float*)d_out;

    hipLaunchKernelGGL(prep_weights, dim3(384), dim3(256), 0, stream,
                       Wss, Wvv, Wsv, Wvs, wstream);
    hipLaunchKernelGGL(si_main, dim3(256), dim3(512), 0, stream, x, wstream, raw);
    hipLaunchKernelGGL(si_finalize, dim3(NBATCH), dim3(64), 0, stream, raw, out);
}

// Round 3
// 203.673 us; speedup vs baseline: 1.7584x; 1.7584x over previous
//
#include <hip/hip_runtime.h>

// SelfInteraction on MI355X.
// R2: static branch-free inner loops (tq == vb), fused cb channel (1 B-load -> 3 MFMA sets),
// each weight byte issued once per block (6 MB), XOR-swizzled x LDS staging.

#define C 128
#define NBATCH 8192

typedef _Float16 f16;
typedef _Float16 f16x8 __attribute__((ext_vector_type(8)));
typedef float f32x4 __attribute__((ext_vector_type(4)));

// ws layout:
// [0, 12MB)  : 3 f16 weight streams (ss, vv*inv_sqrt3, comb=Wsv+Wvs^T), each 2,097,152 f16
//              idx ((((h*4+vb)*128+u)*4+wt)*64+lane)*8+j
//                <-> W[u][vb*32+(lane>>4)*8+j][h*64+wt*16+(lane&15)]
// [12MB,32MB): raw channel sums f32 [5][8192][128]  (ss, vv_scaled, cb0, cb1, cb2)
#define WSTREAM_F16_PER_C (2*4*128*4*64*8)   // 2,097,152 f16 = 4MB
#define NSTREAM 3
#define RAW_OFF_BYTES ((size_t)NSTREAM*WSTREAM_F16_PER_C*2)  // 12 MB

__device__ __forceinline__ f16x8 splat8(f16 v) { return (f16x8){v, v, v, v, v, v, v, v}; }
union U16x8 { uint4 u; f16x8 h; };
__device__ __forceinline__ f16x8 as_h8(uint4 v) { U16x8 x; x.u = v; return x.h; }
__device__ __forceinline__ f32x4 mfma16(f16x8 a, f16x8 b, f32x4 c) {
    return __builtin_amdgcn_mfma_f32_16x16x32_f16(a, b, c, 0, 0, 0);
}
// swizzled LDS index for [col][z] f16 tiles: kills staging bank conflicts,
// keeps compute reads broadcast/conflict-free.
__device__ __forceinline__ int xz(int col, int z) {
    return col * 64 + (z ^ ((col & 31) << 1));
}

// ---------------- weight prep ----------------
__global__ __launch_bounds__(256) void prep_weights(
        const float* __restrict__ Wss, const float* __restrict__ Wvv,
        const float* __restrict__ Wsv, const float* __restrict__ Wvs,
        f16* __restrict__ out) {
    __shared__ float lds[128 * 130];
    int c = blockIdx.x >> 7;
    int u = blockIdx.x & 127;
    if (c == 2) {
        for (int i = threadIdx.x; i < 16384; i += 256) {
            int v = i >> 7, w = i & 127;
            lds[v * 130 + w] = Wsv[(size_t)u * 16384 + i] + Wvs[(size_t)v * 16384 + u * 128 + w];
        }
    } else {
        const float* src = (c == 0 ? Wss : Wvv) + (size_t)u * 16384;
        float sc = (c == 0) ? 1.0f : 0.57735026918962576f;
        for (int i = threadIdx.x; i < 16384; i += 256) {
            int v = i >> 7, w = i & 127;
            lds[v * 130 + w] = sc * src[i];
        }
    }
    __syncthreads();
    f16* dst = out + (size_t)c * WSTREAM_F16_PER_C;
    for (int pos = threadIdx.x; pos < 2048; pos += 256) {
        int h = pos >> 10, vb = (pos >> 8) & 3, wt = (pos >> 6) & 3, l = pos & 63;
        int v0 = vb * 32 + (l >> 4) * 8;
        int w = h * 64 + wt * 16 + (l & 15);
        f16x8 vals;
#pragma unroll
        for (int j = 0; j < 8; ++j) vals[j] = (f16)lds[(v0 + j) * 130 + w];
        size_t off = ((size_t)(((h * 4 + vb) * 128 + u) * 4 + wt) * 64 + l) * 8;
        *(f16x8*)(dst + off) = vals;
    }
}

// phase-1 tile write: 64 rows x 64 cols
__device__ __forceinline__ void writeP1(float* __restrict__ raw, int c, int zb, int h,
        int l15, int lhi, const f32x4 (&acc)[4][4], bool st) {
#pragma unroll
    for (int s = 0; s < 4; ++s)
#pragma unroll
        for (int wt = 0; wt < 4; ++wt)
#pragma unroll
            for (int i = 0; i < 4; ++i) {
                int z = zb * 64 + s * 16 + lhi * 4 + i;
                int col = h * 64 + wt * 16 + l15;
                float* p = &raw[((size_t)c * NBATCH + z) * 128 + col];
                if (st) *p = acc[s][wt][i]; else *p += acc[s][wt][i];
            }
}

// phase-2 tile write: 64 rows x 32 cols (n-half)
__device__ __forceinline__ void writeP2(float* __restrict__ raw, int c, int zb, int h,
        int grp, int l15, int lhi, const f32x4 (&a)[4][2], bool st) {
#pragma unroll
    for (int s = 0; s < 4; ++s)
#pragma unroll
        for (int wtl = 0; wtl < 2; ++wtl)
#pragma unroll
            for (int i = 0; i < 4; ++i) {
                int z = zb * 64 + s * 16 + lhi * 4 + i;
                int col = h * 64 + (grp * 2 + wtl) * 16 + l15;
                float* p = &raw[((size_t)c * NBATCH + z) * 128 + col];
                if (st) *p = a[s][wtl][i]; else *p += a[s][wtl][i];
            }
}

// ---------------- main fused GEMM kernel ----------------
// grid 256: zb = bid>>1, h = bid&1 (h==bid&1 keeps each XCD on one h: stream sharing in L2).
// 8 waves. Phase1: grp=w>>2 (0=ss,1=vv), tq=w&3 = K-quarter = vb. M=64,N=64,128 t-steps.
// Phase2: all waves on fused cb (3 k per B-load): grp=n-half, tq=vb. M=64,N=32,128 t-steps.
__global__ __launch_bounds__(512, 2) void si_main(
        const float* __restrict__ x, const f16* __restrict__ wstream,
        float* __restrict__ raw) {
    __shared__ f16 x0T[128 * 64];       // [c][z] swizzled via xz()
    __shared__ f16 x1T[3 * 128 * 64];   // [k][v][z] swizzled

    int zb = blockIdx.x >> 1;
    int h = blockIdx.x & 1;
    int tid = threadIdx.x;

    for (int i = tid; i < 64 * 512; i += 512) {
        int z = i >> 9, col = i & 511;
        f16 fv = (f16)x[(size_t)(zb * 64 + z) * 512 + col];
        if (col < 128) {
            x0T[xz(col, z)] = fv;
        } else {
            int cc = col - 128;
            int v = cc / 3, k = cc - v * 3;
            x1T[k * 8192 + xz(v, z)] = fv;
        }
    }
    __syncthreads();

    int lane = tid & 63, w = tid >> 6;
    int l15 = lane & 15, lhi = lane >> 4;
    int tq = w & 3;      // K-quarter == vb
    int grp = w >> 2;    // phase1: channel; phase2: n-half

    // ================= phase 1 =================
    f32x4 acc[4][4];
#pragma unroll
    for (int s = 0; s < 4; ++s)
#pragma unroll
        for (int wt = 0; wt < 4; ++wt) acc[s][wt] = (f32x4){0.f, 0.f, 0.f, 0.f};
    {
        const int vb = tq;
        const uint4* blane = (const uint4*)(wstream + (size_t)grp * WSTREAM_F16_PER_C
                                            + (size_t)h * (WSTREAM_F16_PER_C / 2))
                             + (size_t)(vb * 128) * 256 + lhi * 16 + l15;
        uint4 b0[4], b1[4], bf[4];
#pragma unroll
        for (int wt = 0; wt < 4; ++wt) b0[wt] = blane[wt * 64];
#pragma unroll
        for (int wt = 0; wt < 4; ++wt) b1[wt] = blane[256 + wt * 64];

        if (grp == 0) {
            // ss: coeff = x0[z,u]*x0[z,v]
            f16x8 vva[4];
#pragma unroll
            for (int s = 0; s < 4; ++s)
#pragma unroll
                for (int j = 0; j < 8; ++j)
                    vva[s][j] = x0T[xz(vb * 32 + lhi * 8 + j, s * 16 + l15)];
#pragma unroll 4
            for (int uu = 0; uu < 128; ++uu) {
#pragma unroll
                for (int wt = 0; wt < 4; ++wt) bf[wt] = blane[(uu + 2) * 256 + wt * 64];
                f16x8 A[4];
#pragma unroll
                for (int s = 0; s < 4; ++s)
                    A[s] = splat8(x0T[xz(uu, s * 16 + l15)]) * vva[s];
#pragma unroll
                for (int wt = 0; wt < 4; ++wt) {
                    f16x8 B = as_h8(b0[wt]);
#pragma unroll
                    for (int s = 0; s < 4; ++s) acc[s][wt] = mfma16(A[s], B, acc[s][wt]);
                }
#pragma unroll
                for (int wt = 0; wt < 4; ++wt) { b0[wt] = b1[wt]; b1[wt] = bf[wt]; }
            }
        } else {
            // vv: coeff = sum_k x1k[z,u]*x1k[z,v]
            f16x8 v0a[4], v1a[4], v2a[4];
#pragma unroll
            for (int s = 0; s < 4; ++s)
#pragma unroll
                for (int j = 0; j < 8; ++j) {
                    int ci = vb * 32 + lhi * 8 + j, zi = s * 16 + l15;
                    v0a[s][j] = x1T[xz(ci, zi)];
                    v1a[s][j] = x1T[8192 + xz(ci, zi)];
                    v2a[s][j] = x1T[16384 + xz(ci, zi)];
                }
#pragma unroll 4
            for (int uu = 0; uu < 128; ++uu) {
#pragma unroll
                for (int wt = 0; wt < 4; ++wt) bf[wt] = blane[(uu + 2) * 256 + wt * 64];
                f16x8 A[4];
#pragma unroll
                for (int s = 0; s < 4; ++s) {
                    int zi = s * 16 + l15;
                    A[s] = splat8(x1T[xz(uu, zi)]) * v0a[s]
                         + splat8(x1T[8192 + xz(uu, zi)]) * v1a[s]
                         + splat8(x1T[16384 + xz(uu, zi)]) * v2a[s];
                }
#pragma unroll
                for (int wt = 0; wt < 4; ++wt) {
                    f16x8 B = as_h8(b0[wt]);
#pragma unroll
                    for (int s = 0; s < 4; ++s) acc[s][wt] = mfma16(A[s], B, acc[s][wt]);
                }
#pragma unroll
                for (int wt = 0; wt < 4; ++wt) { b0[wt] = b1[wt]; b1[wt] = bf[wt]; }
            }
        }
    }
    // phase1 reduce: per round, wave tq==r writes its channel tile (store at r0, add after)
#pragma unroll
    for (int r = 0; r < 4; ++r) {
        __threadfence_block();
        __syncthreads();
        if (tq == r) writeP1(raw, grp, zb, h, l15, lhi, acc, r == 0);
    }
    __threadfence_block();
    __syncthreads();

    // ================= phase 2: fused cb, 3 k per B-load =================
    f32x4 a2[3][4][2];
#pragma unroll
    for (int k = 0; k < 3; ++k)
#pragma unroll
        for (int s = 0; s < 4; ++s)
#pragma unroll
            for (int wtl = 0; wtl < 2; ++wtl) a2[k][s][wtl] = (f32x4){0.f, 0.f, 0.f, 0.f};
    {
        const int vb = tq;
        f16x8 vva[3][4];
#pragma unroll
        for (int k = 0; k < 3; ++k)
#pragma unroll
            for (int s = 0; s < 4; ++s)
#pragma unroll
                for (int j = 0; j < 8; ++j)
                    vva[k][s][j] = x1T[k * 8192 + xz(vb * 32 + lhi * 8 + j, s * 16 + l15)];

        const uint4* blane = (const uint4*)(wstream + (size_t)2 * WSTREAM_F16_PER_C
                                            + (size_t)h * (WSTREAM_F16_PER_C / 2))
                             + (size_t)(vb * 128) * 256 + (grp * 2) * 64 + lhi * 16 + l15;
        uint4 b0[2], b1[2], bf[2];
#pragma unroll
        for (int wtl = 0; wtl < 2; ++wtl) b0[wtl] = blane[wtl * 64];
#pragma unroll
        for (int wtl = 0; wtl < 2; ++wtl) b1[wtl] = blane[256 + wtl * 64];

#pragma unroll 2
        for (int uu = 0; uu < 128; ++uu) {
#pragma unroll
            for (int wtl = 0; wtl < 2; ++wtl) bf[wtl] = blane[(uu + 2) * 256 + wtl * 64];
            f16 xs[4];
#pragma unroll
            for (int s = 0; s < 4; ++s) xs[s] = x0T[xz(uu, s * 16 + l15)];
#pragma unroll
            for (int k = 0; k < 3; ++k) {
                f16x8 A[4];
#pragma unroll
                for (int s = 0; s < 4; ++s) A[s] = splat8(xs[s]) * vva[k][s];
#pragma unroll
                for (int wtl = 0; wtl < 2; ++wtl) {
                    f16x8 B = as_h8(b0[wtl]);
#pragma unroll
                    for (int s = 0; s < 4; ++s) a2[k][s][wtl] = mfma16(A[s], B, a2[k][s][wtl]);
                }
            }
#pragma unroll
            for (int wtl = 0; wtl < 2; ++wtl) { b0[wtl] = b1[wtl]; b1[wtl] = bf[wtl]; }
        }
    }
    // phase2 reduce: k-rotated rounds; wave (grp,tq) writes cb(kk,grp) at round r, kk=(tq+r)&3
#pragma unroll
    for (int r = 0; r < 4; ++r) {
        __threadfence_block();
        __syncthreads();
        int kk = (tq + r) & 3;
        if (kk < 3) {
            bool st = (r == 0);
            if (kk == 0)      writeP2(raw, 2, zb, h, grp, l15, lhi, a2[0], st);
            else if (kk == 1) writeP2(raw, 3, zb, h, grp, l15, lhi, a2[1], st);
            else              writeP2(raw, 4, zb, h, grp, l15, lhi, a2[2], st);
        }
    }
}

// ---------------- finalize ----------------
__global__ __launch_bounds__(64) void si_finalize(const float* __restrict__ raw,
                                                  float* __restrict__ out) {
    const float PW0 = 0.0055242717280199f;   // 1/sqrt(2*128*128) == pw1/sqrt(3)
    int z = blockIdx.x;
    int t = threadIdx.x;
    const size_t CS = (size_t)NBATCH * 128;
    const float* r0 = raw + (size_t)z * 128;

    float y0A = PW0 * (r0[t] + r0[CS + t]);
    float y0B = PW0 * (r0[t + 64] + r0[CS + t + 64]);
    float s1 = y0A + y0B, s2 = y0A * y0A + y0B * y0B;
    for (int o = 32; o; o >>= 1) {
        s1 += __shfl_xor(s1, o);
        s2 += __shfl_xor(s2, o);
    }
    float mean = s1 * (1.0f / 128.0f);
    float var = (s2 - 128.0f * mean * mean) * (1.0f / 127.0f);
    float sc = 1.0f / (sqrtf(fmaxf(var, 0.0f)) + 1e-9f);
    out[(size_t)z * 512 + t] = y0A * sc;
    out[(size_t)z * 512 + t + 64] = y0B * sc;

    float yA[3], yB[3];
    float nA = 1e-9f, nB = 1e-9f;
#pragma unroll
    for (int k = 0; k < 3; ++k) {
        yA[k] = PW0 * r0[CS * (2 + k) + t];
        yB[k] = PW0 * r0[CS * (2 + k) + t + 64];
        nA += yA[k] * yA[k];
        nB += yB[k] * yB[k];
    }
    nA = sqrtf(nA);
    nB = sqrtf(nB);
    float t1 = nA + nB, t2 = nA * nA + nB * nB;
    for (int o = 32; o; o >>= 1) {
        t1 += __shfl_xor(t1, o);
        t2 += __shfl_xor(t2, o);
    }
    float meanv = t1 * (1.0f / 128.0f);
    float varv = (t2 - 128.0f * meanv * meanv) * (1.0f / 127.0f);
    float sv = 1.0f / (sqrtf(fmaxf(varv, 0.0f)) + 1e-9f);
#pragma unroll
    for (int k = 0; k < 3; ++k) {
        out[(size_t)z * 512 + 128 + t * 3 + k] = yA[k] * sv;
        out[(size_t)z * 512 + 128 + (t + 64) * 3 + k] = yB[k] * sv;
    }
}

extern "C" void kernel_launch(void* const* d_in, const int* in_sizes, int n_in,
                              void* d_out, int out_size, void* d_ws, size_t ws_size,
                              hipStream_t stream) {
    const float* x = (const float*)d_in[0];
    const float* Wss = (const float*)d_in[1];
    const float* Wvv = (const float*)d_in[2];
    const float* Wsv = (const float*)d_in[3];
    const float* Wvs = (const float*)d_in[4];
    f16* wstream = (f16*)d_ws;
    float* raw = (float*)((char*)d_ws + RAW_OFF_BYTES);
    float* out = (float*)d_out;

    hipLaunchKernelGGL(prep_weights, dim3(384), dim3(256), 0, stream,
                       Wss, Wvv, Wsv, Wvs, wstream);
    hipLaunchKernelGGL(si_main, dim3(256), dim3(512), 0, stream, x, wstream, raw);
    hipLaunchKernelGGL(si_finalize, dim3(NBATCH), dim3(64), 0, stream, raw, out);
}